// Round 1
// baseline (344.279 us; speedup 1.0000x reference)
//
#include <hip/hip_runtime.h>
#include <hip/hip_bf16.h>

#define BB 16
#define NN 1024
#define HH 768
#define NEG_INF_ -9.0e15f
#define SLOPE_ 0.2f

typedef __bf16 bh8 __attribute__((ext_vector_type(8)));
typedef __bf16 bh4 __attribute__((ext_vector_type(4)));
typedef float f4 __attribute__((ext_vector_type(4)));

// ---------------- block reductions (256 threads = 4 waves) ----------------

__device__ inline float block_sum_all(float v, float* sbuf) {
    #pragma unroll
    for (int off = 32; off > 0; off >>= 1) v += __shfl_down(v, off, 64);
    const int lane = threadIdx.x & 63, w = threadIdx.x >> 6;
    if (lane == 0) sbuf[w] = v;
    __syncthreads();
    return sbuf[0] + sbuf[1] + sbuf[2] + sbuf[3];
}

__device__ inline float block_max_all(float v, float* sbuf) {
    #pragma unroll
    for (int off = 32; off > 0; off >>= 1) v = fmaxf(v, __shfl_down(v, off, 64));
    const int lane = threadIdx.x & 63, w = threadIdx.x >> 6;
    if (lane == 0) sbuf[w] = v;
    __syncthreads();
    return fmaxf(fmaxf(sbuf[0], sbuf[1]), fmaxf(sbuf[2], sbuf[3]));
}

// ---------------- kernel 1: wa1 = W @ a1, wa2 = W @ a2 ----------------
// grid = HH blocks, 256 threads; block f computes wa1[f], wa2[f].

__global__ __launch_bounds__(256) void wa_kernel(const float* __restrict__ W,
                                                 const float* __restrict__ a,
                                                 float* __restrict__ wa1,
                                                 float* __restrict__ wa2) {
    __shared__ float sb1[4], sb2[4];
    const int f = blockIdx.x;
    float v1 = 0.f, v2 = 0.f;
    for (int j = threadIdx.x; j < HH; j += 256) {
        const float w = W[(size_t)f * HH + j];
        v1 += w * a[j];
        v2 += w * a[HH + j];
    }
    const float r1 = block_sum_all(v1, sb1);
    const float r2 = block_sum_all(v2, sb2);
    if (threadIdx.x == 0) { wa1[f] = r1; wa2[f] = r2; }
}

// ---------------- kernel 2: t1[b,m] = x[b,m,:]·wa1, t2 likewise ----------------
// grid = BB*NN blocks, 256 threads.

__global__ __launch_bounds__(256) void t_kernel(const float* __restrict__ x,
                                                const float* __restrict__ wa1,
                                                const float* __restrict__ wa2,
                                                float* __restrict__ t1,
                                                float* __restrict__ t2) {
    __shared__ float sb1[4], sb2[4];
    const int row = blockIdx.x;
    const float* xr = x + (size_t)row * HH;
    float v1 = 0.f, v2 = 0.f;
    for (int f = threadIdx.x; f < HH; f += 256) {
        const float xv = xr[f];
        v1 += xv * wa1[f];
        v2 += xv * wa2[f];
    }
    const float r1 = block_sum_all(v1, sb1);
    const float r2 = block_sum_all(v2, sb2);
    if (threadIdx.x == 0) { t1[row] = r1; t2[row] = r2; }
}

// ---------------- kernel 3: s1[b,n] = adj[b,n,:]·t1[b,:], s2 likewise ----------------
// grid = BB*NN blocks, 256 threads.

__global__ __launch_bounds__(256) void s_kernel(const float* __restrict__ adj,
                                                const float* __restrict__ t1,
                                                const float* __restrict__ t2,
                                                float* __restrict__ s1,
                                                float* __restrict__ s2) {
    __shared__ float sb1[4], sb2[4];
    const int row = blockIdx.x;           // b*NN + n
    const int b = row >> 10;
    const float* ar = adj + (size_t)row * NN;
    const float* t1b = t1 + (size_t)b * NN;
    const float* t2b = t2 + (size_t)b * NN;
    float v1 = 0.f, v2 = 0.f;
    for (int m = threadIdx.x; m < NN; m += 256) {
        const float av = ar[m];
        v1 += av * t1b[m];
        v2 += av * t2b[m];
    }
    const float r1 = block_sum_all(v1, sb1);
    const float r2 = block_sum_all(v2, sb2);
    if (threadIdx.x == 0) { s1[row] = r1; s2[row] = r2; }
}

// ---------------- kernel 4: masked leaky-relu scores + softmax -> attn ----------------
// grid = BB*NN blocks (one per output row), 256 threads, 4 elems/thread.

__global__ __launch_bounds__(256) void softmax_kernel(const float* __restrict__ adj,
                                                      const float* __restrict__ nl,
                                                      const float* __restrict__ s1,
                                                      const float* __restrict__ s2,
                                                      float* __restrict__ attn) {
    __shared__ float sbm[4], sbs[4];
    const int row = blockIdx.x;           // b*NN + n
    const int b = row >> 10;
    const int n = row & (NN - 1);
    const float* ar = adj + (size_t)row * NN;
    const float* nlb = nl + (size_t)b * NN;
    const float* s2b = s2 + (size_t)b * NN;
    const float s1v = s1[row];
    const float nln = nlb[n];
    const int tid = threadIdx.x;

    float sc[4];
    float mx = NEG_INF_;
    #pragma unroll
    for (int k = 0; k < 4; k++) {
        const int j = tid + k * 256;
        const float z = s1v + s2b[j];
        const float e = z > 0.f ? z : SLOPE_ * z;
        const bool valid = (ar[j] > 1e-6f) && (nln * nlb[j] > 1e-6f);
        sc[k] = valid ? e : NEG_INF_;
        mx = fmaxf(mx, sc[k]);
    }
    const float bmax = block_max_all(mx, sbm);

    float ex[4];
    float sum = 0.f;
    #pragma unroll
    for (int k = 0; k < 4; k++) {
        ex[k] = __expf(sc[k] - bmax);   // NEG_INF-NEG_INF = 0 -> 1 (uniform row), matches JAX
        sum += ex[k];
    }
    const float bsum = block_sum_all(sum, sbs);
    const float inv = 1.0f / bsum;

    float* outr = attn + (size_t)row * NN;
    #pragma unroll
    for (int k = 0; k < 4; k++) outr[tid + k * 256] = ex[k] * inv;
}

// ---------------- kernel 5: node_vec = adj @ x (bf16 MFMA, fp32 acc) ----------------
// 128x128 tile, BK=32, 256 threads (4 waves, each a 64x64 quadrant of 16x16x32 MFMAs).

#define LDT 40   // padded LDS row stride (elems): 80B -> bank starts stride 20 mod 32 (2-way, free)

__global__ __launch_bounds__(256) void gemm_bf16(const float* __restrict__ adj,
                                                 const float* __restrict__ x,
                                                 float* __restrict__ out) {
    __shared__ __bf16 As[128 * LDT];
    __shared__ __bf16 Bs[128 * LDT];
    const int b = blockIdx.z;
    const int bm = blockIdx.y;   // 0..7
    const int bn = blockIdx.x;   // 0..5
    const float* Ab = adj + (size_t)b * NN * NN + (size_t)bm * 128 * NN;
    const float* Xb = x + (size_t)b * NN * HH + bn * 128;
    const int tid = threadIdx.x;
    const int lane = tid & 63;
    const int wave = tid >> 6;
    const int wr = (wave >> 1) << 6;   // wave row offset {0,64}
    const int wc = (wave & 1) << 6;    // wave col offset {0,64}

    f4 acc[4][4];
    #pragma unroll
    for (int i = 0; i < 4; i++)
        #pragma unroll
        for (int j = 0; j < 4; j++)
            acc[i][j] = (f4){0.f, 0.f, 0.f, 0.f};

    // A staging: thread covers rows ra+32*i, cols ca..ca+3 (float4, coalesced per 8 threads)
    const int ra = tid >> 3;           // 0..31
    const int ca = (tid & 7) * 4;      // 0..28
    // B staging (transpose x tile): thread covers k = kB..kB+3, n = nB..nB+3
    const int nB = (tid & 31) * 4;     // 0..124
    const int kB = (tid >> 5) * 4;     // 0..28

    const int quad = lane >> 4;
    const int l16 = lane & 15;
    const int ak = quad * 8;

    for (int kt = 0; kt < NN; kt += 32) {
        __syncthreads();
        // stage A (adj rows are k-contiguous already)
        #pragma unroll
        for (int i = 0; i < 4; i++) {
            const int r = ra + 32 * i;
            const float4 v = *reinterpret_cast<const float4*>(Ab + (size_t)r * NN + kt + ca);
            __bf16* d = &As[r * LDT + ca];
            d[0] = (__bf16)v.x; d[1] = (__bf16)v.y; d[2] = (__bf16)v.z; d[3] = (__bf16)v.w;
        }
        // stage B with transpose: Bs[n][k] = x[kt+k][bn*128+n]
        const float4 q0 = *reinterpret_cast<const float4*>(Xb + (size_t)(kt + kB + 0) * HH + nB);
        const float4 q1 = *reinterpret_cast<const float4*>(Xb + (size_t)(kt + kB + 1) * HH + nB);
        const float4 q2 = *reinterpret_cast<const float4*>(Xb + (size_t)(kt + kB + 2) * HH + nB);
        const float4 q3 = *reinterpret_cast<const float4*>(Xb + (size_t)(kt + kB + 3) * HH + nB);
        {
            __bf16* d0 = &Bs[(nB + 0) * LDT + kB];
            d0[0] = (__bf16)q0.x; d0[1] = (__bf16)q1.x; d0[2] = (__bf16)q2.x; d0[3] = (__bf16)q3.x;
            __bf16* d1 = &Bs[(nB + 1) * LDT + kB];
            d1[0] = (__bf16)q0.y; d1[1] = (__bf16)q1.y; d1[2] = (__bf16)q2.y; d1[3] = (__bf16)q3.y;
            __bf16* d2 = &Bs[(nB + 2) * LDT + kB];
            d2[0] = (__bf16)q0.z; d2[1] = (__bf16)q1.z; d2[2] = (__bf16)q2.z; d2[3] = (__bf16)q3.z;
            __bf16* d3 = &Bs[(nB + 3) * LDT + kB];
            d3[0] = (__bf16)q0.w; d3[1] = (__bf16)q1.w; d3[2] = (__bf16)q2.w; d3[3] = (__bf16)q3.w;
        }
        __syncthreads();

        bh8 af[4], bfr[4];
        #pragma unroll
        for (int i = 0; i < 4; i++) {
            const __bf16* p = &As[(wr + i * 16 + l16) * LDT + ak];
            const bh4 lo = *reinterpret_cast<const bh4*>(p);
            const bh4 hi = *reinterpret_cast<const bh4*>(p + 4);
            af[i] = __builtin_shufflevector(lo, hi, 0, 1, 2, 3, 4, 5, 6, 7);
        }
        #pragma unroll
        for (int j = 0; j < 4; j++) {
            const __bf16* p = &Bs[(wc + j * 16 + l16) * LDT + ak];
            const bh4 lo = *reinterpret_cast<const bh4*>(p);
            const bh4 hi = *reinterpret_cast<const bh4*>(p + 4);
            bfr[j] = __builtin_shufflevector(lo, hi, 0, 1, 2, 3, 4, 5, 6, 7);
        }
        #pragma unroll
        for (int i = 0; i < 4; i++)
            #pragma unroll
            for (int j = 0; j < 4; j++)
                acc[i][j] = __builtin_amdgcn_mfma_f32_16x16x32_bf16(af[i], bfr[j], acc[i][j], 0, 0, 0);
    }

    // epilogue: C/D layout col = lane&15, row = (lane>>4)*4 + reg  [m89-verified]
    float* Cb = out + (size_t)b * NN * HH + (size_t)bm * 128 * HH + bn * 128;
    const int rbase = wr + quad * 4;
    const int cbase = wc + l16;
    #pragma unroll
    for (int i = 0; i < 4; i++)
        #pragma unroll
        for (int j = 0; j < 4; j++)
            #pragma unroll
            for (int r = 0; r < 4; r++)
                Cb[(size_t)(rbase + i * 16 + r) * HH + cbase + j * 16] = acc[i][j][r];
}

// ---------------- launch ----------------

extern "C" void kernel_launch(void* const* d_in, const int* in_sizes, int n_in,
                              void* d_out, int out_size, void* d_ws, size_t ws_size,
                              hipStream_t stream) {
    const float* x   = (const float*)d_in[0];   // (16,1024,768)
    const float* nl  = (const float*)d_in[1];   // (16,1024)
    const float* adj = (const float*)d_in[2];   // (16,1024,1024)
    const float* W   = (const float*)d_in[3];   // (768,768)
    const float* a   = (const float*)d_in[4];   // (1536,1)

    float* out = (float*)d_out;
    float* node_vec = out;                              // 16*1024*768
    float* attn = out + (size_t)BB * NN * HH;           // 16*1024*1024

    float* ws  = (float*)d_ws;
    float* wa1 = ws;                 // 768
    float* wa2 = wa1 + HH;           // 768
    float* t1  = wa2 + HH;           // 16384
    float* t2  = t1 + BB * NN;       // 16384
    float* s1  = t2 + BB * NN;       // 16384
    float* s2  = s1 + BB * NN;       // 16384

    hipLaunchKernelGGL(wa_kernel, dim3(HH), dim3(256), 0, stream, W, a, wa1, wa2);
    hipLaunchKernelGGL(t_kernel, dim3(BB * NN), dim3(256), 0, stream, x, wa1, wa2, t1, t2);
    hipLaunchKernelGGL(s_kernel, dim3(BB * NN), dim3(256), 0, stream, adj, t1, t2, s1, s2);
    hipLaunchKernelGGL(softmax_kernel, dim3(BB * NN), dim3(256), 0, stream, adj, nl, s1, s2, attn);
    hipLaunchKernelGGL(gemm_bf16, dim3(6, 8, BB), dim3(256), 0, stream, adj, x, node_vec);
}

// Round 2
// 274.974 us; speedup vs baseline: 1.2520x; 1.2520x over previous
//
#include <hip/hip_runtime.h>
#include <hip/hip_bf16.h>

#define BB 16
#define NN 1024
#define HH 768
#define NEG_INF_ -9.0e15f
#define SLOPE_ 0.2f

typedef __bf16 bh8 __attribute__((ext_vector_type(8)));
typedef __bf16 bh4 __attribute__((ext_vector_type(4)));
typedef float f4 __attribute__((ext_vector_type(4)));
typedef unsigned int u32;
typedef unsigned long long u64;

// ---------------- wave-level reductions (no LDS, no syncthreads) ----------------

__device__ __forceinline__ float wave_sum0(float v) {       // result valid in lane 0
    #pragma unroll
    for (int off = 32; off > 0; off >>= 1) v += __shfl_down(v, off, 64);
    return v;
}
__device__ __forceinline__ float wave_sum_all(float v) {    // result in all lanes
    #pragma unroll
    for (int off = 1; off < 64; off <<= 1) v += __shfl_xor(v, off, 64);
    return v;
}
__device__ __forceinline__ float wave_max_all(float v) {
    #pragma unroll
    for (int off = 1; off < 64; off <<= 1) v = fmaxf(v, __shfl_xor(v, off, 64));
    return v;
}

// ---------------- async global->LDS 16B ----------------

__device__ __forceinline__ void gl_lds16(const void* g, void* l) {
    __builtin_amdgcn_global_load_lds(
        (const __attribute__((address_space(1))) u32*)g,
        (__attribute__((address_space(3))) u32*)l, 16, 0, 0);
}

// ---------------- kernel 1: wa = W @ a1|a2 -- one wave per output f ----------------
// grid 192 x 256

__global__ __launch_bounds__(256) void wa_kernel(const float* __restrict__ W,
                                                 const float* __restrict__ a,
                                                 float* __restrict__ wa1,
                                                 float* __restrict__ wa2) {
    const int f = blockIdx.x * 4 + (threadIdx.x >> 6);
    const int lane = threadIdx.x & 63;
    const float* Wr = W + (size_t)f * HH;
    float v1 = 0.f, v2 = 0.f;
    #pragma unroll
    for (int i = 0; i < 3; i++) {
        const int h = lane * 4 + i * 256;
        const float4 w  = *(const float4*)(Wr + h);
        const float4 a1 = *(const float4*)(a + h);
        const float4 a2 = *(const float4*)(a + HH + h);
        v1 += w.x * a1.x + w.y * a1.y + w.z * a1.z + w.w * a1.w;
        v2 += w.x * a2.x + w.y * a2.y + w.z * a2.z + w.w * a2.w;
    }
    v1 = wave_sum0(v1);
    v2 = wave_sum0(v2);
    if (lane == 0) { wa1[f] = v1; wa2[f] = v2; }
}

// ---------------- kernel 2: t[row] = x[row,:]·wa -- one wave per row ----------------
// grid 4096 x 256

__global__ __launch_bounds__(256) void t_kernel(const float* __restrict__ x,
                                                const float* __restrict__ wa1,
                                                const float* __restrict__ wa2,
                                                float* __restrict__ t1,
                                                float* __restrict__ t2) {
    const int row = blockIdx.x * 4 + (threadIdx.x >> 6);
    const int lane = threadIdx.x & 63;
    const float* xr = x + (size_t)row * HH;
    float v1 = 0.f, v2 = 0.f;
    #pragma unroll
    for (int i = 0; i < 3; i++) {
        const int h = lane * 4 + i * 256;
        const float4 xv = *(const float4*)(xr + h);
        const float4 w1 = *(const float4*)(wa1 + h);
        const float4 w2 = *(const float4*)(wa2 + h);
        v1 += xv.x * w1.x + xv.y * w1.y + xv.z * w1.z + xv.w * w1.w;
        v2 += xv.x * w2.x + xv.y * w2.y + xv.z * w2.z + xv.w * w2.w;
    }
    v1 = wave_sum0(v1);
    v2 = wave_sum0(v2);
    if (lane == 0) { t1[row] = v1; t2[row] = v2; }
}

// ---------------- kernel 3: x (B,N,H) f32 -> xT (B,H,N) bf16 ----------------
// grid (24 htiles, 32 ntiles, BB) x 256; 32x32 tiles via LDS

__global__ __launch_bounds__(256) void xt_kernel(const float* __restrict__ x,
                                                 __bf16* __restrict__ xT) {
    __shared__ __bf16 T[32][36];
    const int b = blockIdx.z, nt = blockIdx.y, ht = blockIdx.x;
    const int t = threadIdx.x;
    {
        const int r = t >> 3;          // n within tile
        const int c = (t & 7) * 4;     // h within tile
        const float4 v = *(const float4*)(x + ((size_t)b * NN + nt * 32 + r) * HH + ht * 32 + c);
        T[r][c + 0] = (__bf16)v.x; T[r][c + 1] = (__bf16)v.y;
        T[r][c + 2] = (__bf16)v.z; T[r][c + 3] = (__bf16)v.w;
    }
    __syncthreads();
    {
        const int h = t >> 3;          // h within tile
        const int nc = (t & 7) * 4;    // n within tile
        bh4 o = { T[nc + 0][h], T[nc + 1][h], T[nc + 2][h], T[nc + 3][h] };
        *(bh4*)(xT + ((size_t)b * HH + ht * 32 + h) * NN + nt * 32 + nc) = o;
    }
}

// ---------------- kernel 4: s = adj·t + pack adj bits -- one wave per row ----------------
// grid 4096 x 256

__global__ __launch_bounds__(256) void s_pack_kernel(const float* __restrict__ adj,
                                                     const float* __restrict__ t1,
                                                     const float* __restrict__ t2,
                                                     float* __restrict__ s1,
                                                     float* __restrict__ s2,
                                                     u64* __restrict__ bits) {
    const int row = blockIdx.x * 4 + (threadIdx.x >> 6);
    const int lane = threadIdx.x & 63;
    const int b = row >> 10;
    const float* ar = adj + (size_t)row * NN;
    const float* t1b = t1 + b * NN;
    const float* t2b = t2 + b * NN;
    float v1 = 0.f, v2 = 0.f;
    u64 myw = 0;
    #pragma unroll
    for (int i = 0; i < 16; i++) {
        const int m = lane + 64 * i;
        const float av = ar[m];
        v1 += av * t1b[m];
        v2 += av * t2b[m];
        const u64 bal = __ballot(av > 1e-6f);
        if (lane == i) myw = bal;
    }
    v1 = wave_sum0(v1);
    v2 = wave_sum0(v2);
    if (lane == 0) { s1[row] = v1; s2[row] = v2; }
    if (lane < 16) bits[(size_t)row * 16 + lane] = myw;
}

// ---------------- kernel 5: softmax -- one wave per row, registers only ----------------
// grid 4096 x 256

__global__ __launch_bounds__(256) void softmax_kernel(const float* __restrict__ adj,
                                                      const float* __restrict__ nl,
                                                      const float* __restrict__ s1,
                                                      const float* __restrict__ s2,
                                                      float* __restrict__ attn) {
    const int row = blockIdx.x * 4 + (threadIdx.x >> 6);
    const int lane = threadIdx.x & 63;
    const int b = row >> 10, n = row & (NN - 1);
    const float* ar = adj + (size_t)row * NN;
    const float* nlb = nl + (size_t)b * NN;
    const float* s2b = s2 + (size_t)b * NN;
    const float s1v = s1[row];
    const bool rowok = nlb[n] > 1e-6f;

    f4 sc[4];
    float mx = NEG_INF_;
    #pragma unroll
    for (int i = 0; i < 4; i++) {
        const int j = lane * 4 + i * 256;
        const float4 av = *(const float4*)(ar + j);
        const float4 sv = *(const float4*)(s2b + j);
        const float4 nv = *(const float4*)(nlb + j);
        const float zs[4] = { s1v + sv.x, s1v + sv.y, s1v + sv.z, s1v + sv.w };
        const float as_[4] = { av.x, av.y, av.z, av.w };
        const float ns[4] = { nv.x, nv.y, nv.z, nv.w };
        #pragma unroll
        for (int e = 0; e < 4; e++) {
            const float z = zs[e];
            const float lr = z > 0.f ? z : SLOPE_ * z;
            const bool valid = rowok && (as_[e] > 1e-6f) && (ns[e] > 1e-6f);
            sc[i][e] = valid ? lr : NEG_INF_;
            mx = fmaxf(mx, sc[i][e]);
        }
    }
    mx = wave_max_all(mx);

    f4 ex[4];
    float sum = 0.f;
    #pragma unroll
    for (int i = 0; i < 4; i++)
        #pragma unroll
        for (int e = 0; e < 4; e++) {
            ex[i][e] = __expf(sc[i][e] - mx);
            sum += ex[i][e];
        }
    sum = wave_sum_all(sum);
    const float inv = 1.0f / sum;

    float* outr = attn + (size_t)row * NN;
    #pragma unroll
    for (int i = 0; i < 4; i++) {
        const int j = lane * 4 + i * 256;
        float4 o;
        o.x = ex[i][0] * inv; o.y = ex[i][1] * inv;
        o.z = ex[i][2] * inv; o.w = ex[i][3] * inv;
        *(float4*)(outr + j) = o;
    }
}

// ---------------- kernel 6: node_vec = adj @ x via bit-A + bf16-B MFMA ----------------
// grid (6,8,BB) x 256; A expanded from bitmask in LDS (exact), B staged async from xT.

#define BSTRIDE 36   // u32 words per bits row in LDS (pad: rows r, r+8 alias -> 2-way, free)

__global__ __launch_bounds__(256) void gemm_bits(const u32* __restrict__ bits,
                                                 const __bf16* __restrict__ xT,
                                                 float* __restrict__ out) {
    __shared__ u32 bitsL[128 * BSTRIDE];     // 18432 B
    __shared__ __bf16 Bs[128 * 32];          // 8192 B, unpadded (global_load_lds)
    const int b = blockIdx.z, bm = blockIdx.y, bn = blockIdx.x;
    const int tid = threadIdx.x, lane = tid & 63, wave = tid >> 6;
    const int wr = (wave >> 1) << 6;         // wave row offset {0,64}
    const int wc = (wave & 1) << 6;          // wave col offset {0,64}
    const int quad = lane >> 4, l16 = lane & 15;

    // load A bitmask for rows bm*128..+128 (16.5 KB, once per block)
    const u32* bg = bits + ((size_t)b * NN + bm * 128) * 32;
    #pragma unroll
    for (int it = 0; it < 4; it++) {
        const int c = tid + 256 * it;        // 1024 chunks of 4 words
        const int r = c >> 3, col = (c & 7) * 4;
        const uint4 v = *(const uint4*)(bg + r * 32 + col);
        *(uint4*)&bitsL[r * BSTRIDE + col] = v;
    }

    f4 acc[4][4];
    #pragma unroll
    for (int i = 0; i < 4; i++)
        #pragma unroll
        for (int j = 0; j < 4; j++)
            acc[i][j] = (f4){0.f, 0.f, 0.f, 0.f};

    const __bf16* xb = xT + ((size_t)b * HH + bn * 128) * NN;
    __syncthreads();   // bits visible

    for (int kt = 0; kt < NN; kt += 32) {
        // stage Bs[n][k] = xT[bn*128+n][kt+k], async 16B (LDS dest = wavebase + lane*16)
        #pragma unroll
        for (int it = 0; it < 2; it++) {
            const int c = tid + 256 * it;    // 512 chunks
            const int n = c >> 2, off = (c & 3) * 16;
            gl_lds16((const char*)(xb + (size_t)n * NN + kt) + off,
                     (char*)&Bs[n * 32] + off);
        }
        __syncthreads();   // drains vmcnt: Bs ready

        bh8 af[4], bf_[4];
        const int kw = kt >> 5;
        #pragma unroll
        for (int i = 0; i < 4; i++) {
            const u32 w = bitsL[(wr + i * 16 + l16) * BSTRIDE + kw];
            const u32 byte = (w >> (quad * 8)) & 0xffu;
            #pragma unroll
            for (int j = 0; j < 8; j++)
                af[i][j] = ((byte >> j) & 1u) ? (__bf16)1.0f : (__bf16)0.0f;
        }
        #pragma unroll
        for (int j = 0; j < 4; j++)
            bf_[j] = *(const bh8*)&Bs[(wc + j * 16 + l16) * 32 + quad * 8];

        #pragma unroll
        for (int i = 0; i < 4; i++)
            #pragma unroll
            for (int j = 0; j < 4; j++)
                acc[i][j] = __builtin_amdgcn_mfma_f32_16x16x32_bf16(af[i], bf_[j], acc[i][j], 0, 0, 0);
        __syncthreads();   // reads done before next staging overwrites Bs
    }

    // epilogue: C/D layout col = lane&15, row = (lane>>4)*4 + reg  [m89-verified]
    float* Cb = out + (size_t)b * NN * HH + (size_t)bm * 128 * HH + bn * 128;
    const int rbase = wr + quad * 4;
    const int cbase = wc + l16;
    #pragma unroll
    for (int i = 0; i < 4; i++)
        #pragma unroll
        for (int j = 0; j < 4; j++)
            #pragma unroll
            for (int r = 0; r < 4; r++)
                Cb[(size_t)(rbase + i * 16 + r) * HH + cbase + j * 16] = acc[i][j][r];
}

// ---------------- launch ----------------

extern "C" void kernel_launch(void* const* d_in, const int* in_sizes, int n_in,
                              void* d_out, int out_size, void* d_ws, size_t ws_size,
                              hipStream_t stream) {
    const float* x   = (const float*)d_in[0];   // (16,1024,768)
    const float* nl  = (const float*)d_in[1];   // (16,1024)
    const float* adj = (const float*)d_in[2];   // (16,1024,1024)
    const float* W   = (const float*)d_in[3];   // (768,768)
    const float* a   = (const float*)d_in[4];   // (1536,1)

    float* out = (float*)d_out;
    float* node_vec = out;                               // 16*1024*768 floats
    float* attn = out + (size_t)BB * NN * HH;            // 16*1024*1024 floats

    // scratch inside the attn region (consumed by gemm BEFORE softmax overwrites it):
    __bf16* xT = (__bf16*)attn;                          // 24 MB: (B,H,N) bf16
    u64* bits = (u64*)(attn + (size_t)6 * 1024 * 1024);  // +24MB: 2 MB bitmask

    float* ws  = (float*)d_ws;                           // small scratch (~262 KB)
    float* wa1 = ws;
    float* wa2 = wa1 + HH;
    float* t1  = wa2 + HH;
    float* t2  = t1 + BB * NN;
    float* s1  = t2 + BB * NN;
    float* s2  = s1 + BB * NN;

    hipLaunchKernelGGL(wa_kernel, dim3(192), dim3(256), 0, stream, W, a, wa1, wa2);
    hipLaunchKernelGGL(t_kernel, dim3(4096), dim3(256), 0, stream, x, wa1, wa2, t1, t2);
    hipLaunchKernelGGL(xt_kernel, dim3(24, 32, BB), dim3(256), 0, stream, x, xT);
    hipLaunchKernelGGL(s_pack_kernel, dim3(4096), dim3(256), 0, stream, adj, t1, t2, s1, s2, bits);
    hipLaunchKernelGGL(gemm_bits, dim3(6, 8, BB), dim3(256), 0, stream, bits ? (const u32*)bits : nullptr, xT, node_vec);
    hipLaunchKernelGGL(softmax_kernel, dim3(4096), dim3(256), 0, stream, adj, nl, s1, s2, attn);
}